// Round 8
// baseline (222.901 us; speedup 1.0000x reference)
//
#include <hip/hip_runtime.h>
#include <hip/hip_bf16.h>

typedef float f32x4 __attribute__((ext_vector_type(4)));
typedef short s16x8 __attribute__((ext_vector_type(8)));

#define B_ 4
#define S_ 2048
#define D_ 768

typedef const __attribute__((address_space(1))) char* gas_t;
typedef __attribute__((address_space(3))) char* las_t;

__device__ __forceinline__ void gload_lds16(const void* g, void* l) {
  __builtin_amdgcn_global_load_lds((gas_t)g, (las_t)l, 16, 0, 0);
}

// ---------------- f32 -> bf16 conversion ----------------
__global__ void cvt_kernel(const float* __restrict__ x,
                           const float* __restrict__ wq,
                           const float* __restrict__ wk,
                           const float* __restrict__ wv,
                           __hip_bfloat16* __restrict__ xb,
                           __hip_bfloat16* __restrict__ wqb,
                           __hip_bfloat16* __restrict__ wkb,
                           __hip_bfloat16* __restrict__ wvb) {
  const int NX = B_ * S_ * D_ / 4;
  const int NW = D_ * D_ / 4;
  int stride = gridDim.x * blockDim.x;
  for (int j = blockIdx.x * blockDim.x + threadIdx.x; j < NX + 3 * NW; j += stride) {
    const float4* src; __hip_bfloat16* dst; int off;
    if (j < NX)             { src = (const float4*)x;  dst = xb;  off = j; }
    else if (j < NX + NW)   { src = (const float4*)wq; dst = wqb; off = j - NX; }
    else if (j < NX + 2*NW) { src = (const float4*)wk; dst = wkb; off = j - NX - NW; }
    else                    { src = (const float4*)wv; dst = wvb; off = j - NX - 2*NW; }
    float4 v = src[off];
    dst[4*off+0] = __float2bfloat16(v.x);
    dst[4*off+1] = __float2bfloat16(v.y);
    dst[4*off+2] = __float2bfloat16(v.z);
    dst[4*off+3] = __float2bfloat16(v.w);
  }
}

// ---- shared staging helper: stage a 128x64 bf16 tile (row-major, k-contig) ----
// src rows: base + (r0+row)*stride + k0 + col ; LDS: [128][64] linear.
__device__ __forceinline__ void stage_tile64(const __hip_bfloat16* __restrict__ base,
                                             size_t stride, int r0, int k0,
                                             char* lds, int w, int l) {
#pragma unroll
  for (int it = 0; it < 4; ++it) {
    int ra = it * 32 + w * 8 + (l >> 3);
    int ca = (l & 7) * 8;
    gload_lds16(base + (size_t)(r0 + ra) * stride + k0 + ca,
                lds + it * 4096 + w * 1024);
  }
}

// ---------------- QKV projection GEMM (BK=64) ----------------
// z=0: Q = x @ Wq^T ; z=1: K = x @ Wk^T ; z=2: Vt = Wv @ x^T (V transposed [B][768][2048])
__launch_bounds__(256, 4)
__global__ void qkv_gemm(const __hip_bfloat16* __restrict__ xb,
                         const __hip_bfloat16* __restrict__ wqb,
                         const __hip_bfloat16* __restrict__ wkb,
                         const __hip_bfloat16* __restrict__ wvb,
                         __hip_bfloat16* __restrict__ Qb,
                         __hip_bfloat16* __restrict__ Kb,
                         __hip_bfloat16* __restrict__ Vt) {
  __shared__ __hip_bfloat16 At[128 * 64];
  __shared__ __hip_bfloat16 Bt[128 * 64];
  const int z = blockIdx.z;
  const __hip_bfloat16* Ag;
  const __hip_bfloat16* Bg;
  int m0, n0;
  if (z == 0)      { Ag = xb;  Bg = wqb; m0 = blockIdx.x * 128; n0 = blockIdx.y * 128; }
  else if (z == 1) { Ag = xb;  Bg = wkb; m0 = blockIdx.x * 128; n0 = blockIdx.y * 128; }
  else             { Ag = wvb; Bg = xb;  m0 = blockIdx.y * 128; n0 = blockIdx.x * 128; }

  const int tid = threadIdx.x, w = tid >> 6, l = tid & 63;
  const int wr = w >> 1, wc = w & 1;
  f32x4 acc[4][4] = {};

  for (int k0 = 0; k0 < 768; k0 += 64) {
    __syncthreads();
    stage_tile64(Ag, 768, m0, k0, (char*)At, w, l);
    stage_tile64(Bg, 768, n0, k0, (char*)Bt, w, l);
    __syncthreads();
#pragma unroll
    for (int kk = 0; kk < 2; ++kk) {
      s16x8 a[4], b[4];
#pragma unroll
      for (int i = 0; i < 4; ++i) {
        a[i] = *(const s16x8*)&At[(wr * 64 + i * 16 + (l & 15)) * 64 + kk * 32 + (l >> 4) * 8];
        b[i] = *(const s16x8*)&Bt[(wc * 64 + i * 16 + (l & 15)) * 64 + kk * 32 + (l >> 4) * 8];
      }
#pragma unroll
      for (int i = 0; i < 4; ++i)
#pragma unroll
        for (int j = 0; j < 4; ++j)
          acc[i][j] = __builtin_amdgcn_mfma_f32_16x16x32_bf16(a[i], b[j], acc[i][j], 0, 0, 0);
    }
  }

  if (z < 2) {
    __hip_bfloat16* outp = (z == 0) ? Qb : Kb;
#pragma unroll
    for (int i = 0; i < 4; ++i) {
      int m = m0 + wr * 64 + i * 16 + (l >> 4) * 4;
#pragma unroll
      for (int j = 0; j < 4; ++j) {
        int n = n0 + wc * 64 + j * 16 + (l & 15);
#pragma unroll
        for (int r = 0; r < 4; ++r)
          outp[(size_t)(m + r) * 768 + n] = __float2bfloat16(acc[i][j][r]);
      }
    }
  } else {
#pragma unroll
    for (int i = 0; i < 4; ++i) {
      int dd = m0 + wr * 64 + i * 16 + (l >> 4) * 4;
#pragma unroll
      for (int j = 0; j < 4; ++j) {
        int sg = n0 + wc * 64 + j * 16 + (l & 15);
        int bb = sg >> 11, sl = sg & 2047;
#pragma unroll
        for (int r = 0; r < 4; ++r)
          Vt[(size_t)bb * D_ * S_ + (size_t)(dd + r) * S_ + sl] = __float2bfloat16(acc[i][j][r]);
      }
    }
  }
}

// ---------------- S = scale*log2e * Q K^T, causal-masked, bf16 (BK=64) ----------------
__launch_bounds__(256, 4)
__global__ void qk_gemm(const __hip_bfloat16* __restrict__ Qb,
                        const __hip_bfloat16* __restrict__ Kb,
                        __hip_bfloat16* __restrict__ Sb) {
  __shared__ __hip_bfloat16 At[128 * 64];
  __shared__ __hip_bfloat16 Bt[128 * 64];
  const int qt = blockIdx.x, kt = blockIdx.y, b = blockIdx.z;
  if (kt > qt) return;
  const int m0 = qt * 128, n0 = kt * 128;
  const __hip_bfloat16* Ag = Qb + (size_t)b * S_ * D_;
  const __hip_bfloat16* Bg = Kb + (size_t)b * S_ * D_;
  const int tid = threadIdx.x, w = tid >> 6, l = tid & 63;
  const int wr = w >> 1, wc = w & 1;
  const float SC = 0.03608439182435161f * 1.4426950408889634f;  // (1/sqrt(768))*log2(e)
  f32x4 acc[4][4] = {};

  for (int k0 = 0; k0 < D_; k0 += 64) {
    __syncthreads();
    stage_tile64(Ag, D_, m0, k0, (char*)At, w, l);
    stage_tile64(Bg, D_, n0, k0, (char*)Bt, w, l);
    __syncthreads();
#pragma unroll
    for (int kk = 0; kk < 2; ++kk) {
      s16x8 a[4], bfr[4];
#pragma unroll
      for (int i = 0; i < 4; ++i) {
        a[i]   = *(const s16x8*)&At[(wr * 64 + i * 16 + (l & 15)) * 64 + kk * 32 + (l >> 4) * 8];
        bfr[i] = *(const s16x8*)&Bt[(wc * 64 + i * 16 + (l & 15)) * 64 + kk * 32 + (l >> 4) * 8];
      }
#pragma unroll
      for (int i = 0; i < 4; ++i)
#pragma unroll
        for (int j = 0; j < 4; ++j)
          acc[i][j] = __builtin_amdgcn_mfma_f32_16x16x32_bf16(a[i], bfr[j], acc[i][j], 0, 0, 0);
    }
  }

#pragma unroll
  for (int i = 0; i < 4; ++i) {
    int m = m0 + wr * 64 + i * 16 + (l >> 4) * 4;
#pragma unroll
    for (int j = 0; j < 4; ++j) {
      int n = n0 + wc * 64 + j * 16 + (l & 15);
#pragma unroll
      for (int r = 0; r < 4; ++r) {
        float zz = (n > m + r) ? -1e30f : acc[i][j][r] * SC;
        Sb[(size_t)(b * S_ + m + r) * S_ + n] = __float2bfloat16(zz);
      }
    }
  }
}

// ---------------- row softmax: P = exp2(S - m)/sum, bf16 ----------------
__launch_bounds__(256, 4)
__global__ void softmax_kernel(const __hip_bfloat16* __restrict__ Sb,
                               __hip_bfloat16* __restrict__ Pb) {
  const int tid = threadIdx.x, w = tid >> 6, l = tid & 63;
  const int r = blockIdx.x * 4 + w;
  const int q = r & (S_ - 1);
  const int L = ((q >> 7) + 1) << 7;  // row valid length, multiple of 128
  const ushort* srow = (const ushort*)(Sb + (size_t)r * S_);
  ushort* prow = (ushort*)(Pb + (size_t)r * S_);
  f32x4 ch[8];
#pragma unroll
  for (int it = 0; it < 8; ++it) {
    int idx = it * 256 + l * 4;
    if (idx < L) {
      ushort4 u = *(const ushort4*)&srow[idx];
      ch[it].x = __uint_as_float((unsigned)u.x << 16);
      ch[it].y = __uint_as_float((unsigned)u.y << 16);
      ch[it].z = __uint_as_float((unsigned)u.z << 16);
      ch[it].w = __uint_as_float((unsigned)u.w << 16);
    } else {
      ch[it].x = -1e30f; ch[it].y = -1e30f; ch[it].z = -1e30f; ch[it].w = -1e30f;
    }
  }
  float mx = -1e30f;
#pragma unroll
  for (int it = 0; it < 8; ++it)
    mx = fmaxf(mx, fmaxf(fmaxf(ch[it].x, ch[it].y), fmaxf(ch[it].z, ch[it].w)));
#pragma unroll
  for (int d = 1; d < 64; d <<= 1) mx = fmaxf(mx, __shfl_xor(mx, d, 64));
  float sum = 0.f;
#pragma unroll
  for (int it = 0; it < 8; ++it) {
    ch[it].x = exp2f(ch[it].x - mx);
    ch[it].y = exp2f(ch[it].y - mx);
    ch[it].z = exp2f(ch[it].z - mx);
    ch[it].w = exp2f(ch[it].w - mx);
    sum += (ch[it].x + ch[it].y) + (ch[it].z + ch[it].w);
  }
#pragma unroll
  for (int d = 1; d < 64; d <<= 1) sum += __shfl_xor(sum, d, 64);
  const float rinv = 1.0f / sum;
#pragma unroll
  for (int it = 0; it < 8; ++it) {
    int idx = it * 256 + l * 4;
    if (idx < L) {
      __hip_bfloat16 h0 = __float2bfloat16(ch[it].x * rinv);
      __hip_bfloat16 h1 = __float2bfloat16(ch[it].y * rinv);
      __hip_bfloat16 h2 = __float2bfloat16(ch[it].z * rinv);
      __hip_bfloat16 h3 = __float2bfloat16(ch[it].w * rinv);
      ushort4 u;
      u.x = *(ushort*)&h0; u.y = *(ushort*)&h1; u.z = *(ushort*)&h2; u.w = *(ushort*)&h3;
      *(ushort4*)&prow[idx] = u;
    }
  }
}

// ---------------- O = P V (BK=64; K bounded by causal length; long tiles first) ----
__launch_bounds__(256, 4)
__global__ void pv_gemm(const __hip_bfloat16* __restrict__ Pb,
                        const __hip_bfloat16* __restrict__ Vt,
                        float* __restrict__ out) {
  __shared__ __hip_bfloat16 At[128 * 64];
  __shared__ __hip_bfloat16 Bt[128 * 64];
  const int qt = 15 - (int)blockIdx.x, dt = blockIdx.y, b = blockIdx.z;
  const int m0 = qt * 128, n0 = dt * 128;
  const __hip_bfloat16* Ag = Pb + (size_t)b * S_ * S_;
  const __hip_bfloat16* Bg = Vt + (size_t)b * D_ * S_;
  const int tid = threadIdx.x, w = tid >> 6, l = tid & 63;
  const int wr = w >> 1, wc = w & 1;
  const int kmax = (qt + 1) * 128;
  f32x4 acc[4][4] = {};

  for (int k0 = 0; k0 < kmax; k0 += 64) {
    __syncthreads();
    stage_tile64(Ag, S_, m0, k0, (char*)At, w, l);
    stage_tile64(Bg, S_, n0, k0, (char*)Bt, w, l);
    __syncthreads();
#pragma unroll
    for (int kk = 0; kk < 2; ++kk) {
      s16x8 a[4], bfr[4];
#pragma unroll
      for (int i = 0; i < 4; ++i) {
        a[i]   = *(const s16x8*)&At[(wr * 64 + i * 16 + (l & 15)) * 64 + kk * 32 + (l >> 4) * 8];
        bfr[i] = *(const s16x8*)&Bt[(wc * 64 + i * 16 + (l & 15)) * 64 + kk * 32 + (l >> 4) * 8];
      }
#pragma unroll
      for (int i = 0; i < 4; ++i)
#pragma unroll
        for (int j = 0; j < 4; ++j)
          acc[i][j] = __builtin_amdgcn_mfma_f32_16x16x32_bf16(a[i], bfr[j], acc[i][j], 0, 0, 0);
    }
  }

#pragma unroll
  for (int i = 0; i < 4; ++i) {
    int m = m0 + wr * 64 + i * 16 + (l >> 4) * 4;
#pragma unroll
    for (int j = 0; j < 4; ++j) {
      int n = n0 + wc * 64 + j * 16 + (l & 15);
#pragma unroll
      for (int r = 0; r < 4; ++r)
        out[(size_t)(b * S_ + m + r) * D_ + n] = acc[i][j][r];
    }
  }
}

extern "C" void kernel_launch(void* const* d_in, const int* in_sizes, int n_in,
                              void* d_out, int out_size, void* d_ws, size_t ws_size,
                              hipStream_t stream) {
  const float* x  = (const float*)d_in[0];
  const float* wq = (const float*)d_in[1];
  const float* wk = (const float*)d_in[2];
  const float* wv = (const float*)d_in[3];
  char* ws = (char*)d_ws;
  // layout: xb 0..12.58M | w* ..16.12M | Qb ..28.70M | Kb ..41.29M | Vt ..53.87M
  //         Sb 53.87M..87.43M (bf16 scores) | Pb 0..33.55M (reuses dead region)
  __hip_bfloat16* xb  = (__hip_bfloat16*)(ws + 0);
  __hip_bfloat16* wqb = (__hip_bfloat16*)(ws + 12582912);
  __hip_bfloat16* wkb = (__hip_bfloat16*)(ws + 12582912 + 1179648);
  __hip_bfloat16* wvb = (__hip_bfloat16*)(ws + 12582912 + 2 * 1179648);
  __hip_bfloat16* Qb  = (__hip_bfloat16*)(ws + 16121856);
  __hip_bfloat16* Kb  = (__hip_bfloat16*)(ws + 28704768);
  __hip_bfloat16* Vt  = (__hip_bfloat16*)(ws + 41287680);
  __hip_bfloat16* Sb  = (__hip_bfloat16*)(ws + 53870592);
  __hip_bfloat16* Pb  = (__hip_bfloat16*)(ws + 0);

  cvt_kernel<<<2048, 256, 0, stream>>>(x, wq, wk, wv, xb, wqb, wkb, wvb);
  qkv_gemm<<<dim3(64, 6, 3), 256, 0, stream>>>(xb, wqb, wkb, wvb, Qb, Kb, Vt);
  qk_gemm<<<dim3(16, 16, 4), 256, 0, stream>>>(Qb, Kb, Sb);
  softmax_kernel<<<2048, 256, 0, stream>>>(Sb, Pb);
  pv_gemm<<<dim3(16, 6, 4), 256, 0, stream>>>(Pb, Vt, (float*)d_out);
}

// Round 9
// 196.426 us; speedup vs baseline: 1.1348x; 1.1348x over previous
//
#include <hip/hip_runtime.h>
#include <hip/hip_bf16.h>

typedef float f32x4 __attribute__((ext_vector_type(4)));
typedef short s16x8 __attribute__((ext_vector_type(8)));

#define B_ 4
#define S_ 2048
#define D_ 768

typedef const __attribute__((address_space(1))) char* gas_t;
typedef __attribute__((address_space(3))) char* las_t;

__device__ __forceinline__ void gload_lds16(const void* g, void* l) {
  __builtin_amdgcn_global_load_lds((gas_t)g, (las_t)l, 16, 0, 0);
}

// ---------------- f32 -> bf16 conversion ----------------
__global__ void cvt_kernel(const float* __restrict__ x,
                           const float* __restrict__ wq,
                           const float* __restrict__ wk,
                           const float* __restrict__ wv,
                           __hip_bfloat16* __restrict__ xb,
                           __hip_bfloat16* __restrict__ wqb,
                           __hip_bfloat16* __restrict__ wkb,
                           __hip_bfloat16* __restrict__ wvb) {
  const int NX = B_ * S_ * D_ / 4;
  const int NW = D_ * D_ / 4;
  int stride = gridDim.x * blockDim.x;
  for (int j = blockIdx.x * blockDim.x + threadIdx.x; j < NX + 3 * NW; j += stride) {
    const float4* src; __hip_bfloat16* dst; int off;
    if (j < NX)             { src = (const float4*)x;  dst = xb;  off = j; }
    else if (j < NX + NW)   { src = (const float4*)wq; dst = wqb; off = j - NX; }
    else if (j < NX + 2*NW) { src = (const float4*)wk; dst = wkb; off = j - NX - NW; }
    else                    { src = (const float4*)wv; dst = wvb; off = j - NX - 2*NW; }
    float4 v = src[off];
    dst[4*off+0] = __float2bfloat16(v.x);
    dst[4*off+1] = __float2bfloat16(v.y);
    dst[4*off+2] = __float2bfloat16(v.z);
    dst[4*off+3] = __float2bfloat16(v.w);
  }
}

// ---- staging: 128x64 bf16 tile, LDS linear, SOURCE pre-swizzled (rule #21) ----
// LDS(row, slot) holds global(row, slot ^ (row&7)); slot = 16B unit (8 elems).
// Coalescing kept: per 8-lane row-group the full 128B row is fetched, lanes permuted.
__device__ __forceinline__ void stage_tile64(const __hip_bfloat16* __restrict__ base,
                                             size_t stride, int r0, int k0,
                                             char* lds, int w, int l) {
#pragma unroll
  for (int it = 0; it < 4; ++it) {
    int ra = it * 32 + w * 8 + (l >> 3);
    int slot = (l & 7) ^ ((l >> 3) & 7);  // (ra&7) == (l>>3)&7
    gload_lds16(base + (size_t)(r0 + ra) * stride + k0 + slot * 8,
                lds + it * 4096 + w * 1024);
  }
}

// swizzled fragment read: element index for logical (row R, slot s)
#define SWZ_IDX(R, s) ((R) * 64 + (((s) ^ ((R) & 7)) * 8))

// ---------------- QKV projection GEMM (BK=64, dbuf + prefetch + swizzle) ----------------
// z=0: Q = x @ Wq^T ; z=1: K = x @ Wk^T ; z=2: Vt = Wv @ x^T (V transposed [B][768][2048])
__launch_bounds__(256, 2)
__global__ void qkv_gemm(const __hip_bfloat16* __restrict__ xb,
                         const __hip_bfloat16* __restrict__ wqb,
                         const __hip_bfloat16* __restrict__ wkb,
                         const __hip_bfloat16* __restrict__ wvb,
                         __hip_bfloat16* __restrict__ Qb,
                         __hip_bfloat16* __restrict__ Kb,
                         __hip_bfloat16* __restrict__ Vt) {
  __shared__ __hip_bfloat16 At[2][128 * 64];
  __shared__ __hip_bfloat16 Bt[2][128 * 64];
  const int z = blockIdx.z;
  const __hip_bfloat16* Ag;
  const __hip_bfloat16* Bg;
  int m0, n0;
  if (z == 0)      { Ag = xb;  Bg = wqb; m0 = blockIdx.x * 128; n0 = blockIdx.y * 128; }
  else if (z == 1) { Ag = xb;  Bg = wkb; m0 = blockIdx.x * 128; n0 = blockIdx.y * 128; }
  else             { Ag = wvb; Bg = xb;  m0 = blockIdx.y * 128; n0 = blockIdx.x * 128; }

  const int tid = threadIdx.x, w = tid >> 6, l = tid & 63;
  const int wr = w >> 1, wc = w & 1;
  f32x4 acc[4][4] = {};

  stage_tile64(Ag, 768, m0, 0, (char*)At[0], w, l);
  stage_tile64(Bg, 768, n0, 0, (char*)Bt[0], w, l);
  int cur = 0;
  for (int k0 = 0; k0 < 768; k0 += 64) {
    __syncthreads();  // drains prefetch (buf[cur] ready); protects overwrite
    if (k0 + 64 < 768) {
      stage_tile64(Ag, 768, m0, k0 + 64, (char*)At[cur ^ 1], w, l);
      stage_tile64(Bg, 768, n0, k0 + 64, (char*)Bt[cur ^ 1], w, l);
    }
#pragma unroll
    for (int kk = 0; kk < 2; ++kk) {
      s16x8 a[4], b[4];
      int s = kk * 4 + (l >> 4);
#pragma unroll
      for (int i = 0; i < 4; ++i) {
        int Ra = wr * 64 + i * 16 + (l & 15);
        int Rb = wc * 64 + i * 16 + (l & 15);
        a[i] = *(const s16x8*)&At[cur][SWZ_IDX(Ra, s)];
        b[i] = *(const s16x8*)&Bt[cur][SWZ_IDX(Rb, s)];
      }
#pragma unroll
      for (int i = 0; i < 4; ++i)
#pragma unroll
        for (int j = 0; j < 4; ++j)
          acc[i][j] = __builtin_amdgcn_mfma_f32_16x16x32_bf16(a[i], b[j], acc[i][j], 0, 0, 0);
    }
    cur ^= 1;
  }

  if (z < 2) {
    __hip_bfloat16* outp = (z == 0) ? Qb : Kb;
#pragma unroll
    for (int i = 0; i < 4; ++i) {
      int m = m0 + wr * 64 + i * 16 + (l >> 4) * 4;
#pragma unroll
      for (int j = 0; j < 4; ++j) {
        int n = n0 + wc * 64 + j * 16 + (l & 15);
#pragma unroll
        for (int r = 0; r < 4; ++r)
          outp[(size_t)(m + r) * 768 + n] = __float2bfloat16(acc[i][j][r]);
      }
    }
  } else {
#pragma unroll
    for (int i = 0; i < 4; ++i) {
      int dd = m0 + wr * 64 + i * 16 + (l >> 4) * 4;
#pragma unroll
      for (int j = 0; j < 4; ++j) {
        int sg = n0 + wc * 64 + j * 16 + (l & 15);
        int bb = sg >> 11, sl = sg & 2047;
#pragma unroll
        for (int r = 0; r < 4; ++r)
          Vt[(size_t)bb * D_ * S_ + (size_t)(dd + r) * S_ + sl] = __float2bfloat16(acc[i][j][r]);
      }
    }
  }
}

// ---------------- S = scale*log2e * Q K^T, causal-masked, bf16 ----------------
__launch_bounds__(256, 2)
__global__ void qk_gemm(const __hip_bfloat16* __restrict__ Qb,
                        const __hip_bfloat16* __restrict__ Kb,
                        __hip_bfloat16* __restrict__ Sb) {
  __shared__ __hip_bfloat16 At[2][128 * 64];
  __shared__ __hip_bfloat16 Bt[2][128 * 64];
  const int qt = blockIdx.x, kt = blockIdx.y, b = blockIdx.z;
  if (kt > qt) return;
  const int m0 = qt * 128, n0 = kt * 128;
  const __hip_bfloat16* Ag = Qb + (size_t)b * S_ * D_;
  const __hip_bfloat16* Bg = Kb + (size_t)b * S_ * D_;
  const int tid = threadIdx.x, w = tid >> 6, l = tid & 63;
  const int wr = w >> 1, wc = w & 1;
  const float SC = 0.03608439182435161f * 1.4426950408889634f;  // (1/sqrt(768))*log2(e)
  f32x4 acc[4][4] = {};

  stage_tile64(Ag, D_, m0, 0, (char*)At[0], w, l);
  stage_tile64(Bg, D_, n0, 0, (char*)Bt[0], w, l);
  int cur = 0;
  for (int k0 = 0; k0 < D_; k0 += 64) {
    __syncthreads();
    if (k0 + 64 < D_) {
      stage_tile64(Ag, D_, m0, k0 + 64, (char*)At[cur ^ 1], w, l);
      stage_tile64(Bg, D_, n0, k0 + 64, (char*)Bt[cur ^ 1], w, l);
    }
#pragma unroll
    for (int kk = 0; kk < 2; ++kk) {
      s16x8 a[4], bfr[4];
      int s = kk * 4 + (l >> 4);
#pragma unroll
      for (int i = 0; i < 4; ++i) {
        int Ra = wr * 64 + i * 16 + (l & 15);
        int Rb = wc * 64 + i * 16 + (l & 15);
        a[i]   = *(const s16x8*)&At[cur][SWZ_IDX(Ra, s)];
        bfr[i] = *(const s16x8*)&Bt[cur][SWZ_IDX(Rb, s)];
      }
#pragma unroll
      for (int i = 0; i < 4; ++i)
#pragma unroll
        for (int j = 0; j < 4; ++j)
          acc[i][j] = __builtin_amdgcn_mfma_f32_16x16x32_bf16(a[i], bfr[j], acc[i][j], 0, 0, 0);
    }
    cur ^= 1;
  }

#pragma unroll
  for (int i = 0; i < 4; ++i) {
    int m = m0 + wr * 64 + i * 16 + (l >> 4) * 4;
#pragma unroll
    for (int j = 0; j < 4; ++j) {
      int n = n0 + wc * 64 + j * 16 + (l & 15);
#pragma unroll
      for (int r = 0; r < 4; ++r) {
        float zz = (n > m + r) ? -1e30f : acc[i][j][r] * SC;
        Sb[(size_t)(b * S_ + m + r) * S_ + n] = __float2bfloat16(zz);
      }
    }
  }
}

// ---------------- row softmax: P = exp2(S - m)/sum, bf16 ----------------
__launch_bounds__(256, 4)
__global__ void softmax_kernel(const __hip_bfloat16* __restrict__ Sb,
                               __hip_bfloat16* __restrict__ Pb) {
  const int tid = threadIdx.x, w = tid >> 6, l = tid & 63;
  const int r = blockIdx.x * 4 + w;
  const int q = r & (S_ - 1);
  const int L = ((q >> 7) + 1) << 7;  // row valid length, multiple of 128
  const ushort* srow = (const ushort*)(Sb + (size_t)r * S_);
  ushort* prow = (ushort*)(Pb + (size_t)r * S_);
  f32x4 ch[8];
#pragma unroll
  for (int it = 0; it < 8; ++it) {
    int idx = it * 256 + l * 4;
    if (idx < L) {
      ushort4 u = *(const ushort4*)&srow[idx];
      ch[it].x = __uint_as_float((unsigned)u.x << 16);
      ch[it].y = __uint_as_float((unsigned)u.y << 16);
      ch[it].z = __uint_as_float((unsigned)u.z << 16);
      ch[it].w = __uint_as_float((unsigned)u.w << 16);
    } else {
      ch[it].x = -1e30f; ch[it].y = -1e30f; ch[it].z = -1e30f; ch[it].w = -1e30f;
    }
  }
  float mx = -1e30f;
#pragma unroll
  for (int it = 0; it < 8; ++it)
    mx = fmaxf(mx, fmaxf(fmaxf(ch[it].x, ch[it].y), fmaxf(ch[it].z, ch[it].w)));
#pragma unroll
  for (int d = 1; d < 64; d <<= 1) mx = fmaxf(mx, __shfl_xor(mx, d, 64));
  float sum = 0.f;
#pragma unroll
  for (int it = 0; it < 8; ++it) {
    ch[it].x = exp2f(ch[it].x - mx);
    ch[it].y = exp2f(ch[it].y - mx);
    ch[it].z = exp2f(ch[it].z - mx);
    ch[it].w = exp2f(ch[it].w - mx);
    sum += (ch[it].x + ch[it].y) + (ch[it].z + ch[it].w);
  }
#pragma unroll
  for (int d = 1; d < 64; d <<= 1) sum += __shfl_xor(sum, d, 64);
  const float rinv = 1.0f / sum;
#pragma unroll
  for (int it = 0; it < 8; ++it) {
    int idx = it * 256 + l * 4;
    if (idx < L) {
      __hip_bfloat16 h0 = __float2bfloat16(ch[it].x * rinv);
      __hip_bfloat16 h1 = __float2bfloat16(ch[it].y * rinv);
      __hip_bfloat16 h2 = __float2bfloat16(ch[it].z * rinv);
      __hip_bfloat16 h3 = __float2bfloat16(ch[it].w * rinv);
      ushort4 u;
      u.x = *(ushort*)&h0; u.y = *(ushort*)&h1; u.z = *(ushort*)&h2; u.w = *(ushort*)&h3;
      *(ushort4*)&prow[idx] = u;
    }
  }
}

// ---------------- O = P V (causal-bounded K; long tiles first; dbuf + swizzle) ----
__launch_bounds__(256, 2)
__global__ void pv_gemm(const __hip_bfloat16* __restrict__ Pb,
                        const __hip_bfloat16* __restrict__ Vt,
                        float* __restrict__ out) {
  __shared__ __hip_bfloat16 At[2][128 * 64];
  __shared__ __hip_bfloat16 Bt[2][128 * 64];
  const int qt = 15 - (int)blockIdx.x, dt = blockIdx.y, b = blockIdx.z;
  const int m0 = qt * 128, n0 = dt * 128;
  const __hip_bfloat16* Ag = Pb + (size_t)b * S_ * S_;
  const __hip_bfloat16* Bg = Vt + (size_t)b * D_ * S_;
  const int tid = threadIdx.x, w = tid >> 6, l = tid & 63;
  const int wr = w >> 1, wc = w & 1;
  const int kmax = (qt + 1) * 128;
  f32x4 acc[4][4] = {};

  stage_tile64(Ag, S_, m0, 0, (char*)At[0], w, l);
  stage_tile64(Bg, S_, n0, 0, (char*)Bt[0], w, l);
  int cur = 0;
  for (int k0 = 0; k0 < kmax; k0 += 64) {
    __syncthreads();
    if (k0 + 64 < kmax) {
      stage_tile64(Ag, S_, m0, k0 + 64, (char*)At[cur ^ 1], w, l);
      stage_tile64(Bg, S_, n0, k0 + 64, (char*)Bt[cur ^ 1], w, l);
    }
#pragma unroll
    for (int kk = 0; kk < 2; ++kk) {
      s16x8 a[4], bfr[4];
      int s = kk * 4 + (l >> 4);
#pragma unroll
      for (int i = 0; i < 4; ++i) {
        int Ra = wr * 64 + i * 16 + (l & 15);
        int Rb = wc * 64 + i * 16 + (l & 15);
        a[i]   = *(const s16x8*)&At[cur][SWZ_IDX(Ra, s)];
        bfr[i] = *(const s16x8*)&Bt[cur][SWZ_IDX(Rb, s)];
      }
#pragma unroll
      for (int i = 0; i < 4; ++i)
#pragma unroll
        for (int j = 0; j < 4; ++j)
          acc[i][j] = __builtin_amdgcn_mfma_f32_16x16x32_bf16(a[i], bfr[j], acc[i][j], 0, 0, 0);
    }
    cur ^= 1;
  }

#pragma unroll
  for (int i = 0; i < 4; ++i) {
    int m = m0 + wr * 64 + i * 16 + (l >> 4) * 4;
#pragma unroll
    for (int j = 0; j < 4; ++j) {
      int n = n0 + wc * 64 + j * 16 + (l & 15);
#pragma unroll
      for (int r = 0; r < 4; ++r)
        out[(size_t)(b * S_ + m + r) * D_ + n] = acc[i][j][r];
    }
  }
}

extern "C" void kernel_launch(void* const* d_in, const int* in_sizes, int n_in,
                              void* d_out, int out_size, void* d_ws, size_t ws_size,
                              hipStream_t stream) {
  const float* x  = (const float*)d_in[0];
  const float* wq = (const float*)d_in[1];
  const float* wk = (const float*)d_in[2];
  const float* wv = (const float*)d_in[3];
  char* ws = (char*)d_ws;
  // layout: xb 0..12.58M | w* ..16.12M | Qb ..28.70M | Kb ..41.29M | Vt ..53.87M
  //         Sb 53.87M..87.43M (bf16 scores) | Pb 0..33.55M (reuses dead region)
  __hip_bfloat16* xb  = (__hip_bfloat16*)(ws + 0);
  __hip_bfloat16* wqb = (__hip_bfloat16*)(ws + 12582912);
  __hip_bfloat16* wkb = (__hip_bfloat16*)(ws + 12582912 + 1179648);
  __hip_bfloat16* wvb = (__hip_bfloat16*)(ws + 12582912 + 2 * 1179648);
  __hip_bfloat16* Qb  = (__hip_bfloat16*)(ws + 16121856);
  __hip_bfloat16* Kb  = (__hip_bfloat16*)(ws + 28704768);
  __hip_bfloat16* Vt  = (__hip_bfloat16*)(ws + 41287680);
  __hip_bfloat16* Sb  = (__hip_bfloat16*)(ws + 53870592);
  __hip_bfloat16* Pb  = (__hip_bfloat16*)(ws + 0);

  cvt_kernel<<<2048, 256, 0, stream>>>(x, wq, wk, wv, xb, wqb, wkb, wvb);
  qkv_gemm<<<dim3(64, 6, 3), 256, 0, stream>>>(xb, wqb, wkb, wvb, Qb, Kb, Vt);
  qk_gemm<<<dim3(16, 16, 4), 256, 0, stream>>>(Qb, Kb, Sb);
  softmax_kernel<<<2048, 256, 0, stream>>>(Sb, Pb);
  pv_gemm<<<dim3(16, 6, 4), 256, 0, stream>>>(Pb, Vt, (float*)d_out);
}